// Round 1
// baseline (7375.362 us; speedup 1.0000x reference)
//
#include <hip/hip_runtime.h>
#include <hip/hip_bf16.h>

// GraphSAGE(2-layer, mean agg) + 3-layer MLP link predictor.
// N=100000 nodes, E=1.6M edges, E_PAIR=100000, D=128.

#define D 128
#define SCAN_B 512

// ---------------- CSR build ----------------
__global__ void k_count_deg(const int* __restrict__ dst, int* __restrict__ cnt, int e) {
    int i = blockIdx.x * 256 + threadIdx.x;
    if (i < e) atomicAdd(&cnt[dst[i]], 1);
}

__global__ void k_scan_block(const int* __restrict__ deg, int* __restrict__ row_off,
                             int* __restrict__ bsums, int n) {
    __shared__ int s[SCAN_B];
    int i = blockIdx.x * SCAN_B + threadIdx.x;
    int v = (i < n) ? deg[i] : 0;
    s[threadIdx.x] = v;
    __syncthreads();
    for (int off = 1; off < SCAN_B; off <<= 1) {
        int add = (threadIdx.x >= off) ? s[threadIdx.x - off] : 0;
        __syncthreads();
        s[threadIdx.x] += add;
        __syncthreads();
    }
    if (i < n) row_off[i + 1] = s[threadIdx.x];
    if (threadIdx.x == SCAN_B - 1) bsums[blockIdx.x] = s[threadIdx.x];
}

__global__ void k_scan_sums(int* __restrict__ bsums, int nb) {
    if (blockIdx.x == 0 && threadIdx.x == 0) {
        int run = 0;
        for (int b = 0; b < nb; ++b) { int t = bsums[b]; bsums[b] = run; run += t; }
    }
}

__global__ void k_scan_add(int* __restrict__ row_off, const int* __restrict__ bsums, int n) {
    int i = blockIdx.x * SCAN_B + threadIdx.x;
    if (i < n) row_off[i + 1] += bsums[blockIdx.x];
    if (i == 0) row_off[0] = 0;
}

__global__ void k_scatter(const int* __restrict__ src, const int* __restrict__ dst,
                          const int* __restrict__ row_off, int* __restrict__ cursor,
                          int* __restrict__ csr, int e) {
    int i = blockIdx.x * 256 + threadIdx.x;
    if (i < e) {
        int d = dst[i];
        int p = atomicAdd(&cursor[d], 1);
        csr[row_off[d] + p] = src[i];
    }
}

// ---------------- fused SAGE layer: mean-agg + dual GEMV ----------------
// one 128-thread block per node; thread t owns feature/output channel t.
__global__ __launch_bounds__(128) void k_sage_layer(
    const float* __restrict__ X, const int* __restrict__ row_off,
    const int* __restrict__ csr_src,
    const float* __restrict__ Wn, const float* __restrict__ Ws,
    const float* __restrict__ bias, float* __restrict__ out,
    int do_relu) {
    int n = blockIdx.x;
    int t = threadIdx.x;
    __shared__ float s_x[D];
    __shared__ float s_m[D];

    int beg = row_off[n], end = row_off[n + 1];
    float acc = 0.f;
    for (int i = beg; i < end; ++i) {
        int s = csr_src[i];
        acc += X[(size_t)s * D + t];
    }
    float deg = (float)(end - beg);
    s_m[t] = acc / fmaxf(deg, 1.f);
    s_x[t] = X[(size_t)n * D + t];
    __syncthreads();

    const float4* ws4 = reinterpret_cast<const float4*>(Ws + (size_t)t * D);
    const float4* wn4 = reinterpret_cast<const float4*>(Wn + (size_t)t * D);
    float o = bias[t];
    #pragma unroll 8
    for (int k4 = 0; k4 < D / 4; ++k4) {
        float4 ws = ws4[k4];
        float4 wn = wn4[k4];
        int k = k4 * 4;
        o += s_x[k] * ws.x + s_x[k + 1] * ws.y + s_x[k + 2] * ws.z + s_x[k + 3] * ws.w;
        o += s_m[k] * wn.x + s_m[k + 1] * wn.y + s_m[k + 2] * wn.z + s_m[k + 3] * wn.w;
    }
    if (do_relu) o = fmaxf(o, 0.f);
    out[(size_t)n * D + t] = o;
}

// ---------------- link predictor MLP ----------------
// one 128-thread block per pair.
__global__ __launch_bounds__(128) void k_predictor(
    const float* __restrict__ H, const int* __restrict__ src, const int* __restrict__ dst,
    const float* __restrict__ P1w, const float* __restrict__ P1b,
    const float* __restrict__ P2w, const float* __restrict__ P2b,
    const float* __restrict__ P3w, const float* __restrict__ P3b,
    float* __restrict__ out, int n_pairs) {
    int p = blockIdx.x;
    if (p >= n_pairs) return;
    int t = threadIdx.x;
    __shared__ float s_cat[2 * D];
    __shared__ float s_h1[D];
    __shared__ float s_h2[D];
    __shared__ float s_red[2];

    int sN = src[p], dN = dst[p];
    s_cat[t] = H[(size_t)sN * D + t];
    s_cat[D + t] = H[(size_t)dN * D + t];
    __syncthreads();

    // P1: 256 -> 128, relu
    {
        const float4* w4 = reinterpret_cast<const float4*>(P1w + (size_t)t * 2 * D);
        float o = P1b[t];
        #pragma unroll 8
        for (int k4 = 0; k4 < 2 * D / 4; ++k4) {
            float4 w = w4[k4];
            int k = k4 * 4;
            o += s_cat[k] * w.x + s_cat[k + 1] * w.y + s_cat[k + 2] * w.z + s_cat[k + 3] * w.w;
        }
        s_h1[t] = fmaxf(o, 0.f);
    }
    __syncthreads();

    // P2: 128 -> 128, relu
    {
        const float4* w4 = reinterpret_cast<const float4*>(P2w + (size_t)t * D);
        float o = P2b[t];
        #pragma unroll 8
        for (int k4 = 0; k4 < D / 4; ++k4) {
            float4 w = w4[k4];
            int k = k4 * 4;
            o += s_h1[k] * w.x + s_h1[k + 1] * w.y + s_h1[k + 2] * w.z + s_h1[k + 3] * w.w;
        }
        s_h2[t] = fmaxf(o, 0.f);
    }
    __syncthreads();

    // P3: 128 -> 1 (reduce across the block)
    float v = s_h2[t] * P3w[t];
    v += __shfl_down(v, 32);
    v += __shfl_down(v, 16);
    v += __shfl_down(v, 8);
    v += __shfl_down(v, 4);
    v += __shfl_down(v, 2);
    v += __shfl_down(v, 1);
    if ((t & 63) == 0) s_red[t >> 6] = v;
    __syncthreads();
    if (t == 0) out[p] = s_red[0] + s_red[1] + P3b[0];
}

static inline size_t align_up(size_t x, size_t a) { return (x + a - 1) & ~(a - 1); }

extern "C" void kernel_launch(void* const* d_in, const int* in_sizes, int n_in,
                              void* d_out, int out_size, void* d_ws, size_t ws_size,
                              hipStream_t stream) {
    const float* x        = (const float*)d_in[0];
    const int*   edge_src = (const int*)d_in[1];
    const int*   edge_dst = (const int*)d_in[2];
    const int*   pos_src  = (const int*)d_in[3];
    const int*   pos_dst  = (const int*)d_in[4];
    const int*   neg_src  = (const int*)d_in[5];
    const int*   neg_dst  = (const int*)d_in[6];
    const float* W1n = (const float*)d_in[7];
    const float* W1s = (const float*)d_in[8];
    const float* b1  = (const float*)d_in[9];
    const float* W2n = (const float*)d_in[10];
    const float* W2s = (const float*)d_in[11];
    const float* b2  = (const float*)d_in[12];
    const float* P1w = (const float*)d_in[13];
    const float* P1b = (const float*)d_in[14];
    const float* P2w = (const float*)d_in[15];
    const float* P2b = (const float*)d_in[16];
    const float* P3w = (const float*)d_in[17];
    const float* P3b = (const float*)d_in[18];
    float* out = (float*)d_out;

    const int N = in_sizes[0] / D;
    const int E = in_sizes[1];
    const int EP = in_sizes[3];

    // workspace layout
    char* ws = (char*)d_ws;
    size_t off = 0;
    int* row_off = (int*)(ws + off); off = align_up(off + (size_t)(N + 1) * 4, 256);
    int* cursor  = (int*)(ws + off); off = align_up(off + (size_t)N * 4, 256);
    int* bsums   = (int*)(ws + off); off = align_up(off + 4096, 256);
    int* csr     = (int*)(ws + off); off = align_up(off + (size_t)E * 4, 256);
    float* h1    = (float*)(ws + off); off = align_up(off + (size_t)N * D * 4, 256);
    float* h2    = (float*)(ws + off); off = align_up(off + (size_t)N * D * 4, 256);
    (void)ws_size;

    const int nb_scan = (N + SCAN_B - 1) / SCAN_B;

    // --- CSR build ---
    hipMemsetAsync(cursor, 0, (size_t)N * 4, stream);
    k_count_deg<<<(E + 255) / 256, 256, 0, stream>>>(edge_dst, cursor, E);
    k_scan_block<<<nb_scan, SCAN_B, 0, stream>>>(cursor, row_off, bsums, N);
    k_scan_sums<<<1, 64, 0, stream>>>(bsums, nb_scan);
    k_scan_add<<<nb_scan, SCAN_B, 0, stream>>>(row_off, bsums, N);
    hipMemsetAsync(cursor, 0, (size_t)N * 4, stream);
    k_scatter<<<(E + 255) / 256, 256, 0, stream>>>(edge_src, edge_dst, row_off, cursor, csr, E);

    // --- layer 1 (relu) ---
    k_sage_layer<<<N, D, 0, stream>>>(x, row_off, csr, W1n, W1s, b1, h1, 1);
    // --- layer 2 (no relu) ---
    k_sage_layer<<<N, D, 0, stream>>>(h1, row_off, csr, W2n, W2s, b2, h2, 0);

    // --- predictor: pos then neg ---
    k_predictor<<<EP, D, 0, stream>>>(h2, pos_src, pos_dst, P1w, P1b, P2w, P2b, P3w, P3b, out, EP);
    k_predictor<<<EP, D, 0, stream>>>(h2, neg_src, neg_dst, P1w, P1b, P2w, P2b, P3w, P3b, out + EP, EP);
}

// Round 2
// 1452.736 us; speedup vs baseline: 5.0769x; 5.0769x over previous
//
#include <hip/hip_runtime.h>
#include <hip/hip_bf16.h>

// GraphSAGE(2-layer, mean agg) + 3-layer MLP link predictor.
// N=100000 nodes, E=1.6M edges, E_PAIR=100000, D=128.
// Round 2: all dense work as LDS-tiled fp32 GEMMs (32-row tiles), fused predictor.

#define D 128
#define MT 32          // rows per tile
#define KC 64          // k-chunk
#define SCAN_B 512

// ---------------- CSR build ----------------
__global__ void k_count_deg(const int* __restrict__ dst, int* __restrict__ cnt, int e) {
    int i = blockIdx.x * 256 + threadIdx.x;
    if (i < e) atomicAdd(&cnt[dst[i]], 1);
}

__global__ void k_scan_block(const int* __restrict__ deg, int* __restrict__ row_off,
                             int* __restrict__ bsums, int n) {
    __shared__ int s[SCAN_B];
    int i = blockIdx.x * SCAN_B + threadIdx.x;
    int v = (i < n) ? deg[i] : 0;
    s[threadIdx.x] = v;
    __syncthreads();
    for (int off = 1; off < SCAN_B; off <<= 1) {
        int add = (threadIdx.x >= off) ? s[threadIdx.x - off] : 0;
        __syncthreads();
        s[threadIdx.x] += add;
        __syncthreads();
    }
    if (i < n) row_off[i + 1] = s[threadIdx.x];
    if (threadIdx.x == SCAN_B - 1) bsums[blockIdx.x] = s[threadIdx.x];
}

__global__ void k_scan_sums(int* __restrict__ bsums, int nb) {
    if (blockIdx.x == 0 && threadIdx.x == 0) {
        int run = 0;
        for (int b = 0; b < nb; ++b) { int t = bsums[b]; bsums[b] = run; run += t; }
    }
}

__global__ void k_scan_add(int* __restrict__ row_off, const int* __restrict__ bsums, int n) {
    int i = blockIdx.x * SCAN_B + threadIdx.x;
    if (i < n) row_off[i + 1] += bsums[blockIdx.x];
    if (i == 0) row_off[0] = 0;
}

__global__ void k_scatter(const int* __restrict__ src, const int* __restrict__ dst,
                          const int* __restrict__ row_off, int* __restrict__ cursor,
                          int* __restrict__ csr, int e) {
    int i = blockIdx.x * 256 + threadIdx.x;
    if (i < e) {
        int d = dst[i];
        int p = atomicAdd(&cursor[d], 1);
        csr[row_off[d] + p] = src[i];
    }
}

// ---------------- weight transpose: W[O][K] -> Wt[K][O] ----------------
__global__ void k_transpose(const float* __restrict__ src, float* __restrict__ dst,
                            int O, int K) {
    int i = blockIdx.x * 256 + threadIdx.x;
    if (i < O * K) {
        int o = i / K, k = i % K;
        dst[k * O + o] = src[i];
    }
}

// ---------------- mean aggregation ----------------
__global__ __launch_bounds__(128) void k_agg(
    const float* __restrict__ X, const int* __restrict__ row_off,
    const int* __restrict__ csr, float* __restrict__ Agg) {
    int n = blockIdx.x;
    int t = threadIdx.x;
    int beg = row_off[n], end = row_off[n + 1];
    float acc = 0.f;
    for (int i = beg; i < end; ++i) {
        int s = csr[i];
        acc += X[(size_t)s * D + t];
    }
    Agg[(size_t)n * D + t] = acc / fmaxf((float)(end - beg), 1.f);
}

// ---------------- layer transform: out = relu?([X|Agg] @ Wt + b) ----------------
// Wt is [256][128] (k-major, pre-transposed, rows 0..127 = W_self, 128..255 = W_neigh).
// Tile: 32 rows x 128 cols, 256 threads, acc[2][8] per thread.
__global__ __launch_bounds__(256) void k_transform(
    const float* __restrict__ X, const float* __restrict__ Agg,
    const float* __restrict__ Wt, const float* __restrict__ bias,
    float* __restrict__ out, int n_rows, int do_relu) {
    __shared__ float s_a[KC][MT + 4];    // transposed A chunk: s_a[k][r]
    __shared__ float s_w[KC][D + 4];     // W chunk: s_w[k][o]
    int tid = threadIdx.x;
    int rg = tid >> 4, cg = tid & 15;    // rg: 0..15 row group, cg: 0..15 col group
    int n0 = blockIdx.x * MT;
    float acc[2][8];
    #pragma unroll
    for (int i = 0; i < 2; ++i)
        #pragma unroll
        for (int j = 0; j < 8; ++j) acc[i][j] = 0.f;

    for (int c = 0; c < 4; ++c) {
        const float* abase = (c < 2) ? X : Agg;
        int kbase = (c & 1) * KC;
        // stage A chunk (32 rows x 64 k), transposed
        for (int e = tid; e < MT * KC; e += 256) {
            int r = e >> 6, kk = e & 63;
            int n = n0 + r;
            s_a[kk][r] = (n < n_rows) ? abase[(size_t)n * D + kbase + kk] : 0.f;
        }
        // stage W chunk (64 k x 128 o)
        const float* wsrc = Wt + (size_t)c * KC * D;
        for (int e = tid; e < KC * D; e += 256) {
            int kk = e >> 7, o = e & 127;
            s_w[kk][o] = wsrc[e];
        }
        __syncthreads();
        #pragma unroll
        for (int k = 0; k < KC; ++k) {
            float2 a = *(const float2*)&s_a[k][rg * 2];
            float4 w0 = *(const float4*)&s_w[k][cg * 8];
            float4 w1 = *(const float4*)&s_w[k][cg * 8 + 4];
            acc[0][0] += a.x * w0.x; acc[0][1] += a.x * w0.y;
            acc[0][2] += a.x * w0.z; acc[0][3] += a.x * w0.w;
            acc[0][4] += a.x * w1.x; acc[0][5] += a.x * w1.y;
            acc[0][6] += a.x * w1.z; acc[0][7] += a.x * w1.w;
            acc[1][0] += a.y * w0.x; acc[1][1] += a.y * w0.y;
            acc[1][2] += a.y * w0.z; acc[1][3] += a.y * w0.w;
            acc[1][4] += a.y * w1.x; acc[1][5] += a.y * w1.y;
            acc[1][6] += a.y * w1.z; acc[1][7] += a.y * w1.w;
        }
        __syncthreads();
    }

    float4 b0 = *(const float4*)&bias[cg * 8];
    float4 b1 = *(const float4*)&bias[cg * 8 + 4];
    #pragma unroll
    for (int i = 0; i < 2; ++i) {
        int n = n0 + rg * 2 + i;
        if (n >= n_rows) continue;
        float4 v0 = make_float4(acc[i][0] + b0.x, acc[i][1] + b0.y,
                                acc[i][2] + b0.z, acc[i][3] + b0.w);
        float4 v1 = make_float4(acc[i][4] + b1.x, acc[i][5] + b1.y,
                                acc[i][6] + b1.z, acc[i][7] + b1.w);
        if (do_relu) {
            v0.x = fmaxf(v0.x, 0.f); v0.y = fmaxf(v0.y, 0.f);
            v0.z = fmaxf(v0.z, 0.f); v0.w = fmaxf(v0.w, 0.f);
            v1.x = fmaxf(v1.x, 0.f); v1.y = fmaxf(v1.y, 0.f);
            v1.z = fmaxf(v1.z, 0.f); v1.w = fmaxf(v1.w, 0.f);
        }
        *(float4*)&out[(size_t)n * D + cg * 8] = v0;
        *(float4*)&out[(size_t)n * D + cg * 8 + 4] = v1;
    }
}

// ---------------- fused predictor: P1 -> relu -> P2 -> relu -> P3 ----------------
// handles pos (p < EP) and neg (p >= EP) pairs in one grid; 32 pairs per block.
__global__ __launch_bounds__(256) void k_mlp(
    const float* __restrict__ H,
    const int* __restrict__ pos_src, const int* __restrict__ pos_dst,
    const int* __restrict__ neg_src, const int* __restrict__ neg_dst,
    const float* __restrict__ P1wt, const float* __restrict__ P1b,
    const float* __restrict__ P2wt, const float* __restrict__ P2b,
    const float* __restrict__ P3w, const float* __restrict__ P3b,
    float* __restrict__ out, int EP) {
    __shared__ float s_a[KC][MT + 4];      // gathered cat chunk, transposed
    __shared__ float s_w[KC][D + 4];       // weight chunk
    __shared__ float s_h1[D][MT + 4];      // h1 transposed (bank-swizzled rows)
    __shared__ int s_src[MT], s_dst[MT];
    int tid = threadIdx.x;
    int rg = tid >> 4, cg = tid & 15;
    int p0 = blockIdx.x * MT;
    int twoEP = 2 * EP;

    if (tid < MT) {
        int p = p0 + tid;
        int s = 0, d = 0;
        if (p < EP) { s = pos_src[p]; d = pos_dst[p]; }
        else if (p < twoEP) { s = neg_src[p - EP]; d = neg_dst[p - EP]; }
        s_src[tid] = s; s_dst[tid] = d;
    }
    __syncthreads();

    float acc[2][8];
    #pragma unroll
    for (int i = 0; i < 2; ++i)
        #pragma unroll
        for (int j = 0; j < 8; ++j) acc[i][j] = 0.f;

    // ---- P1: [32 x 256] x [256 x 128] ----
    for (int c = 0; c < 4; ++c) {
        int kbase = (c & 1) * KC;
        for (int e = tid; e < MT * KC; e += 256) {
            int r = e >> 6, kk = e & 63;
            int n = (c < 2) ? s_src[r] : s_dst[r];
            s_a[kk][r] = H[(size_t)n * D + kbase + kk];
        }
        const float* wsrc = P1wt + (size_t)c * KC * D;
        for (int e = tid; e < KC * D; e += 256) {
            int kk = e >> 7, o = e & 127;
            s_w[kk][o] = wsrc[e];
        }
        __syncthreads();
        #pragma unroll
        for (int k = 0; k < KC; ++k) {
            float2 a = *(const float2*)&s_a[k][rg * 2];
            float4 w0 = *(const float4*)&s_w[k][cg * 8];
            float4 w1 = *(const float4*)&s_w[k][cg * 8 + 4];
            acc[0][0] += a.x * w0.x; acc[0][1] += a.x * w0.y;
            acc[0][2] += a.x * w0.z; acc[0][3] += a.x * w0.w;
            acc[0][4] += a.x * w1.x; acc[0][5] += a.x * w1.y;
            acc[0][6] += a.x * w1.z; acc[0][7] += a.x * w1.w;
            acc[1][0] += a.y * w0.x; acc[1][1] += a.y * w0.y;
            acc[1][2] += a.y * w0.z; acc[1][3] += a.y * w0.w;
            acc[1][4] += a.y * w1.x; acc[1][5] += a.y * w1.y;
            acc[1][6] += a.y * w1.z; acc[1][7] += a.y * w1.w;
        }
        __syncthreads();
    }

    // relu + bias, write h1 transposed into LDS with XOR-swizzled row index
    {
        float4 b0 = *(const float4*)&P1b[cg * 8];
        float4 b1 = *(const float4*)&P1b[cg * 8 + 4];
        float bb[8] = {b0.x, b0.y, b0.z, b0.w, b1.x, b1.y, b1.z, b1.w};
        #pragma unroll
        for (int i = 0; i < 2; ++i) {
            int r = rg * 2 + i;
            #pragma unroll
            for (int j = 0; j < 8; ++j) {
                int k = cg * 8 + j;
                float v = fmaxf(acc[i][j] + bb[j], 0.f);
                s_h1[k][r ^ ((k >> 3) << 1)] = v;   // swizzle: r ^ 2*cg
            }
        }
    }

    // ---- P2: [32 x 128] x [128 x 128], A from s_h1 ----
    float acc2[2][8];
    #pragma unroll
    for (int i = 0; i < 2; ++i)
        #pragma unroll
        for (int j = 0; j < 8; ++j) acc2[i][j] = 0.f;

    for (int c2 = 0; c2 < 2; ++c2) {
        const float* wsrc = P2wt + (size_t)c2 * KC * D;
        for (int e = tid; e < KC * D; e += 256) {
            int kk = e >> 7, o = e & 127;
            s_w[kk][o] = wsrc[e];
        }
        __syncthreads();   // also orders s_h1 writes before reads (c2==0)
        #pragma unroll
        for (int k = 0; k < KC; ++k) {
            int kg = c2 * KC + k;
            int sw = (kg >> 3) << 1;
            float2 a = *(const float2*)&s_h1[kg][(rg * 2) ^ sw];
            float4 w0 = *(const float4*)&s_w[k][cg * 8];
            float4 w1 = *(const float4*)&s_w[k][cg * 8 + 4];
            acc2[0][0] += a.x * w0.x; acc2[0][1] += a.x * w0.y;
            acc2[0][2] += a.x * w0.z; acc2[0][3] += a.x * w0.w;
            acc2[0][4] += a.x * w1.x; acc2[0][5] += a.x * w1.y;
            acc2[0][6] += a.x * w1.z; acc2[0][7] += a.x * w1.w;
            acc2[1][0] += a.y * w0.x; acc2[1][1] += a.y * w0.y;
            acc2[1][2] += a.y * w0.z; acc2[1][3] += a.y * w0.w;
            acc2[1][4] += a.y * w1.x; acc2[1][5] += a.y * w1.y;
            acc2[1][6] += a.y * w1.z; acc2[1][7] += a.y * w1.w;
        }
        __syncthreads();
    }

    // ---- P3: relu(h2) . P3w, reduce across 16 col-groups (within-wave) ----
    float4 b0 = *(const float4*)&P2b[cg * 8];
    float4 b1 = *(const float4*)&P2b[cg * 8 + 4];
    float bb[8] = {b0.x, b0.y, b0.z, b0.w, b1.x, b1.y, b1.z, b1.w};
    float4 p0v = *(const float4*)&P3w[cg * 8];
    float4 p1v = *(const float4*)&P3w[cg * 8 + 4];
    float pw[8] = {p0v.x, p0v.y, p0v.z, p0v.w, p1v.x, p1v.y, p1v.z, p1v.w};
    float p3bias = P3b[0];
    #pragma unroll
    for (int i = 0; i < 2; ++i) {
        float dot = 0.f;
        #pragma unroll
        for (int j = 0; j < 8; ++j) {
            float h2 = fmaxf(acc2[i][j] + bb[j], 0.f);
            dot += h2 * pw[j];
        }
        dot += __shfl_xor(dot, 1);
        dot += __shfl_xor(dot, 2);
        dot += __shfl_xor(dot, 4);
        dot += __shfl_xor(dot, 8);
        if (cg == 0) {
            int p = p0 + rg * 2 + i;
            if (p < twoEP) out[p] = dot + p3bias;
        }
    }
}

static inline size_t align_up(size_t x, size_t a) { return (x + a - 1) & ~(a - 1); }

extern "C" void kernel_launch(void* const* d_in, const int* in_sizes, int n_in,
                              void* d_out, int out_size, void* d_ws, size_t ws_size,
                              hipStream_t stream) {
    const float* x        = (const float*)d_in[0];
    const int*   edge_src = (const int*)d_in[1];
    const int*   edge_dst = (const int*)d_in[2];
    const int*   pos_src  = (const int*)d_in[3];
    const int*   pos_dst  = (const int*)d_in[4];
    const int*   neg_src  = (const int*)d_in[5];
    const int*   neg_dst  = (const int*)d_in[6];
    const float* W1n = (const float*)d_in[7];
    const float* W1s = (const float*)d_in[8];
    const float* b1  = (const float*)d_in[9];
    const float* W2n = (const float*)d_in[10];
    const float* W2s = (const float*)d_in[11];
    const float* b2  = (const float*)d_in[12];
    const float* P1w = (const float*)d_in[13];
    const float* P1b = (const float*)d_in[14];
    const float* P2w = (const float*)d_in[15];
    const float* P2b = (const float*)d_in[16];
    const float* P3w = (const float*)d_in[17];
    const float* P3b = (const float*)d_in[18];
    float* out = (float*)d_out;

    const int N = in_sizes[0] / D;
    const int E = in_sizes[1];
    const int EP = in_sizes[3];

    // workspace layout
    char* ws = (char*)d_ws;
    size_t off = 0;
    int* row_off = (int*)(ws + off); off = align_up(off + (size_t)(N + 1) * 4, 256);
    int* cursor  = (int*)(ws + off); off = align_up(off + (size_t)N * 4, 256);
    int* bsums   = (int*)(ws + off); off = align_up(off + 4096, 256);
    int* csr     = (int*)(ws + off); off = align_up(off + (size_t)E * 4, 256);
    float* agg   = (float*)(ws + off); off = align_up(off + (size_t)N * D * 4, 256);
    float* h1    = (float*)(ws + off); off = align_up(off + (size_t)N * D * 4, 256);
    float* h2    = (float*)(ws + off); off = align_up(off + (size_t)N * D * 4, 256);
    float* Wt1   = (float*)(ws + off); off = align_up(off + (size_t)2 * D * D * 4, 256);
    float* Wt2   = (float*)(ws + off); off = align_up(off + (size_t)2 * D * D * 4, 256);
    float* P1wt  = (float*)(ws + off); off = align_up(off + (size_t)2 * D * D * 4, 256);
    float* P2wt  = (float*)(ws + off); off = align_up(off + (size_t)D * D * 4, 256);
    (void)ws_size;

    const int nb_scan = (N + SCAN_B - 1) / SCAN_B;
    const int ntile_n = (N + MT - 1) / MT;
    const int ntile_p = (2 * EP + MT - 1) / MT;

    // --- CSR build ---
    hipMemsetAsync(cursor, 0, (size_t)N * 4, stream);
    k_count_deg<<<(E + 255) / 256, 256, 0, stream>>>(edge_dst, cursor, E);
    k_scan_block<<<nb_scan, SCAN_B, 0, stream>>>(cursor, row_off, bsums, N);
    k_scan_sums<<<1, 64, 0, stream>>>(bsums, nb_scan);
    k_scan_add<<<nb_scan, SCAN_B, 0, stream>>>(row_off, bsums, N);
    hipMemsetAsync(cursor, 0, (size_t)N * 4, stream);
    k_scatter<<<(E + 255) / 256, 256, 0, stream>>>(edge_src, edge_dst, row_off, cursor, csr, E);

    // --- weight transposes (k-major) ---
    const int TB = (D * D + 255) / 256;
    k_transpose<<<TB, 256, 0, stream>>>(W1s, Wt1, D, D);             // rows 0..127: self
    k_transpose<<<TB, 256, 0, stream>>>(W1n, Wt1 + D * D, D, D);     // rows 128..255: neigh
    k_transpose<<<TB, 256, 0, stream>>>(W2s, Wt2, D, D);
    k_transpose<<<TB, 256, 0, stream>>>(W2n, Wt2 + D * D, D, D);
    k_transpose<<<2 * TB, 256, 0, stream>>>(P1w, P1wt, D, 2 * D);
    k_transpose<<<TB, 256, 0, stream>>>(P2w, P2wt, D, D);

    // --- layer 1 ---
    k_agg<<<N, 128, 0, stream>>>(x, row_off, csr, agg);
    k_transform<<<ntile_n, 256, 0, stream>>>(x, agg, Wt1, b1, h1, N, 1);
    // --- layer 2 ---
    k_agg<<<N, 128, 0, stream>>>(h1, row_off, csr, agg);
    k_transform<<<ntile_n, 256, 0, stream>>>(h1, agg, Wt2, b2, h2, N, 0);

    // --- fused predictor (pos + neg) ---
    k_mlp<<<ntile_p, 256, 0, stream>>>(h2, pos_src, pos_dst, neg_src, neg_dst,
                                       P1wt, P1b, P2wt, P2b, P3w, P3b, out, EP);
}

// Round 3
// 906.335 us; speedup vs baseline: 8.1376x; 1.6029x over previous
//
#include <hip/hip_runtime.h>
#include <hip/hip_bf16.h>

// GraphSAGE(2-layer, mean agg) + 3-layer MLP link predictor.
// N=100000, E=1.6M, E_PAIR=100000, D=128.
// Round 3: broadcast-W vector GEMM (lane owns 2 rows x 16 cols), conflict-free
// LDS, 32-lane-group aggregation.

#define D 128
#define SCAN_B 512
#define AS 33            // s_a row stride (floats): 2-way banks = free
#define WS 132           // s_w row stride (floats): 16B aligned, rotated banks

// ---------------- CSR build ----------------
__global__ void k_count_deg(const int* __restrict__ dst, int* __restrict__ cnt, int e) {
    int i = blockIdx.x * 256 + threadIdx.x;
    if (i < e) atomicAdd(&cnt[dst[i]], 1);
}

__global__ void k_scan_block(const int* __restrict__ deg, int* __restrict__ row_off,
                             int* __restrict__ bsums, int n) {
    __shared__ int s[SCAN_B];
    int i = blockIdx.x * SCAN_B + threadIdx.x;
    int v = (i < n) ? deg[i] : 0;
    s[threadIdx.x] = v;
    __syncthreads();
    for (int off = 1; off < SCAN_B; off <<= 1) {
        int add = (threadIdx.x >= off) ? s[threadIdx.x - off] : 0;
        __syncthreads();
        s[threadIdx.x] += add;
        __syncthreads();
    }
    if (i < n) row_off[i + 1] = s[threadIdx.x];
    if (threadIdx.x == SCAN_B - 1) bsums[blockIdx.x] = s[threadIdx.x];
}

__global__ void k_scan_sums(int* __restrict__ bsums, int nb) {
    if (blockIdx.x == 0 && threadIdx.x == 0) {
        int run = 0;
        for (int b = 0; b < nb; ++b) { int t = bsums[b]; bsums[b] = run; run += t; }
    }
}

__global__ void k_scan_add(int* __restrict__ row_off, const int* __restrict__ bsums, int n) {
    int i = blockIdx.x * SCAN_B + threadIdx.x;
    if (i < n) row_off[i + 1] += bsums[blockIdx.x];
    if (i == 0) row_off[0] = 0;
}

__global__ void k_scatter(const int* __restrict__ src, const int* __restrict__ dst,
                          const int* __restrict__ row_off, int* __restrict__ cursor,
                          int* __restrict__ csr, int e) {
    int i = blockIdx.x * 256 + threadIdx.x;
    if (i < e) {
        int d = dst[i];
        int p = atomicAdd(&cursor[d], 1);
        csr[row_off[d] + p] = src[i];
    }
}

// ---------------- weight transpose: W[O][K] -> Wt[K][O] ----------------
__global__ void k_transpose(const float* __restrict__ src, float* __restrict__ dst,
                            int O, int K) {
    int i = blockIdx.x * 256 + threadIdx.x;
    if (i < O * K) {
        int o = i / K, k = i % K;
        dst[k * O + o] = src[i];
    }
}

// ---------------- mean aggregation: one 32-lane group per node ----------------
__global__ __launch_bounds__(256) void k_agg(
    const float* __restrict__ X, const int* __restrict__ row_off,
    const int* __restrict__ csr, float* __restrict__ Agg, int n_nodes) {
    int g = blockIdx.x * 8 + (threadIdx.x >> 5);
    if (g >= n_nodes) return;
    int l = threadIdx.x & 31;
    int beg = row_off[g], end = row_off[g + 1];
    float4 a0 = make_float4(0.f, 0.f, 0.f, 0.f);
    float4 a1 = make_float4(0.f, 0.f, 0.f, 0.f);
    int i = beg;
    for (; i + 2 <= end; i += 2) {
        int s0 = csr[i], s1 = csr[i + 1];
        float4 v0 = *(const float4*)(X + (size_t)s0 * D + l * 4);
        float4 v1 = *(const float4*)(X + (size_t)s1 * D + l * 4);
        a0.x += v0.x; a0.y += v0.y; a0.z += v0.z; a0.w += v0.w;
        a1.x += v1.x; a1.y += v1.y; a1.z += v1.z; a1.w += v1.w;
    }
    if (i < end) {
        int s0 = csr[i];
        float4 v0 = *(const float4*)(X + (size_t)s0 * D + l * 4);
        a0.x += v0.x; a0.y += v0.y; a0.z += v0.z; a0.w += v0.w;
    }
    float inv = 1.0f / fmaxf((float)(end - beg), 1.0f);
    float4 o;
    o.x = (a0.x + a1.x) * inv; o.y = (a0.y + a1.y) * inv;
    o.z = (a0.z + a1.z) * inv; o.w = (a0.w + a1.w) * inv;
    *(float4*)(Agg + (size_t)g * D + l * 4) = o;
}

#define FMA16(ACC, A, W0, W1, W2, W3)                                       \
    ACC[0]  += (A) * W0.x; ACC[1]  += (A) * W0.y; ACC[2]  += (A) * W0.z;    \
    ACC[3]  += (A) * W0.w; ACC[4]  += (A) * W1.x; ACC[5]  += (A) * W1.y;    \
    ACC[6]  += (A) * W1.z; ACC[7]  += (A) * W1.w; ACC[8]  += (A) * W2.x;    \
    ACC[9]  += (A) * W2.y; ACC[10] += (A) * W2.z; ACC[11] += (A) * W2.w;    \
    ACC[12] += (A) * W3.x; ACC[13] += (A) * W3.y; ACC[14] += (A) * W3.z;    \
    ACC[15] += (A) * W3.w;

// ---------------- layer transform: out = relu?([X|Agg] @ Wt + b) ----------------
// 512 threads, tile 128 rows x 128 cols; wave w owns cols [16w,16w+16);
// lane owns rows {lane, lane+64}. W reads are wave-uniform broadcasts.
__global__ __launch_bounds__(512) void k_transform(
    const float* __restrict__ X, const float* __restrict__ Agg,
    const float* __restrict__ Wt, const float* __restrict__ bias,
    float* __restrict__ out, int n_rows, int do_relu) {
    __shared__ float s_a[128 * AS];
    __shared__ float s_w[32 * WS];
    int tid = threadIdx.x;
    int w = tid >> 6, lane = tid & 63;
    int c0 = w * 16;
    int a0base = lane * AS, a1base = (lane + 64) * AS;
    int n0 = blockIdx.x * 128;
    int r = tid >> 2, q = tid & 3;           // staging: 4 threads per row
    int nstage = n0 + r; if (nstage >= n_rows) nstage = n_rows - 1;

    float acc0[16], acc1[16];
    #pragma unroll
    for (int j = 0; j < 16; ++j) { acc0[j] = 0.f; acc1[j] = 0.f; }

    for (int c = 0; c < 8; ++c) {
        const float* abase = (c < 4) ? X : Agg;
        int kbase = (c & 3) * 32;
        const float* srcp = abase + (size_t)nstage * D + kbase + q * 8;
        float4 v0 = *(const float4*)srcp;
        float4 v1 = *(const float4*)(srcp + 4);
        const float* wsrc = Wt + (size_t)c * 32 * D + tid * 8;
        float4 u0 = *(const float4*)wsrc;
        float4 u1 = *(const float4*)(wsrc + 4);
        __syncthreads();
        float* ap = s_a + r * AS + q * 8;
        ap[0] = v0.x; ap[1] = v0.y; ap[2] = v0.z; ap[3] = v0.w;
        ap[4] = v1.x; ap[5] = v1.y; ap[6] = v1.z; ap[7] = v1.w;
        float* wp = s_w + (tid >> 4) * WS + (tid & 15) * 8;
        *(float4*)wp = u0; *((float4*)wp + 1) = u1;
        __syncthreads();
        #pragma unroll 8
        for (int kk = 0; kk < 32; ++kk) {
            float a0 = s_a[a0base + kk];
            float a1 = s_a[a1base + kk];
            const float4* wr = (const float4*)(s_w + kk * WS + c0);
            float4 w0 = wr[0], w1 = wr[1], w2 = wr[2], w3 = wr[3];
            FMA16(acc0, a0, w0, w1, w2, w3);
            FMA16(acc1, a1, w0, w1, w2, w3);
        }
    }

    float4 b0 = *(const float4*)(bias + c0);
    float4 b1 = *(const float4*)(bias + c0 + 4);
    float4 b2 = *(const float4*)(bias + c0 + 8);
    float4 b3 = *(const float4*)(bias + c0 + 12);
    float bb[16] = {b0.x, b0.y, b0.z, b0.w, b1.x, b1.y, b1.z, b1.w,
                    b2.x, b2.y, b2.z, b2.w, b3.x, b3.y, b3.z, b3.w};
    #pragma unroll
    for (int rr = 0; rr < 2; ++rr) {
        int n = n0 + lane + rr * 64;
        if (n >= n_rows) continue;
        float* ac = rr ? acc1 : acc0;
        float* op = out + (size_t)n * D + c0;
        #pragma unroll
        for (int j4 = 0; j4 < 4; ++j4) {
            float4 v;
            v.x = ac[j4 * 4 + 0] + bb[j4 * 4 + 0];
            v.y = ac[j4 * 4 + 1] + bb[j4 * 4 + 1];
            v.z = ac[j4 * 4 + 2] + bb[j4 * 4 + 2];
            v.w = ac[j4 * 4 + 3] + bb[j4 * 4 + 3];
            if (do_relu) {
                v.x = fmaxf(v.x, 0.f); v.y = fmaxf(v.y, 0.f);
                v.z = fmaxf(v.z, 0.f); v.w = fmaxf(v.w, 0.f);
            }
            *(float4*)(op + j4 * 4) = v;
        }
    }
}

// ---------------- fused predictor ----------------
__global__ __launch_bounds__(512) void k_mlp(
    const float* __restrict__ H,
    const int* __restrict__ pos_src, const int* __restrict__ pos_dst,
    const int* __restrict__ neg_src, const int* __restrict__ neg_dst,
    const float* __restrict__ P1wt, const float* __restrict__ P1b,
    const float* __restrict__ P2wt, const float* __restrict__ P2b,
    const float* __restrict__ P3w, const float* __restrict__ P3b,
    float* __restrict__ out, int EP) {
    __shared__ float s_a[128 * AS];
    __shared__ float s_w[32 * WS];
    __shared__ float s_red[128 * 8];
    __shared__ int s_src[128], s_dst[128];
    int tid = threadIdx.x;
    int w = tid >> 6, lane = tid & 63;
    int c0 = w * 16;
    int a0base = lane * AS, a1base = (lane + 64) * AS;
    int p0 = blockIdx.x * 128;
    int twoEP = 2 * EP;
    int r = tid >> 2, q = tid & 3;

    if (tid < 128) {
        int p = p0 + tid;
        int s = 0, d = 0;
        if (p < EP) { s = pos_src[p]; d = pos_dst[p]; }
        else if (p < twoEP) { s = neg_src[p - EP]; d = neg_dst[p - EP]; }
        s_src[tid] = s; s_dst[tid] = d;
    }
    __syncthreads();

    float acc0[16], acc1[16];
    #pragma unroll
    for (int j = 0; j < 16; ++j) { acc0[j] = 0.f; acc1[j] = 0.f; }

    // ---- P1: [128 x 256] @ [256 x 128] ----
    for (int c = 0; c < 8; ++c) {
        int node = (c < 4) ? s_src[r] : s_dst[r];
        int kbase = (c & 3) * 32;
        const float* srcp = H + (size_t)node * D + kbase + q * 8;
        float4 v0 = *(const float4*)srcp;
        float4 v1 = *(const float4*)(srcp + 4);
        const float* wsrc = P1wt + (size_t)c * 32 * D + tid * 8;
        float4 u0 = *(const float4*)wsrc;
        float4 u1 = *(const float4*)(wsrc + 4);
        __syncthreads();
        float* ap = s_a + r * AS + q * 8;
        ap[0] = v0.x; ap[1] = v0.y; ap[2] = v0.z; ap[3] = v0.w;
        ap[4] = v1.x; ap[5] = v1.y; ap[6] = v1.z; ap[7] = v1.w;
        float* wp = s_w + (tid >> 4) * WS + (tid & 15) * 8;
        *(float4*)wp = u0; *((float4*)wp + 1) = u1;
        __syncthreads();
        #pragma unroll 8
        for (int kk = 0; kk < 32; ++kk) {
            float a0 = s_a[a0base + kk];
            float a1 = s_a[a1base + kk];
            const float4* wr = (const float4*)(s_w + kk * WS + c0);
            float4 w0 = wr[0], w1 = wr[1], w2 = wr[2], w3 = wr[3];
            FMA16(acc0, a0, w0, w1, w2, w3);
            FMA16(acc1, a1, w0, w1, w2, w3);
        }
    }

    // h1 = relu(acc + P1b)
    {
        float4 b0 = *(const float4*)(P1b + c0);
        float4 b1 = *(const float4*)(P1b + c0 + 4);
        float4 b2 = *(const float4*)(P1b + c0 + 8);
        float4 b3 = *(const float4*)(P1b + c0 + 12);
        float bb[16] = {b0.x, b0.y, b0.z, b0.w, b1.x, b1.y, b1.z, b1.w,
                        b2.x, b2.y, b2.z, b2.w, b3.x, b3.y, b3.z, b3.w};
        #pragma unroll
        for (int j = 0; j < 16; ++j) {
            acc0[j] = fmaxf(acc0[j] + bb[j], 0.f);
            acc1[j] = fmaxf(acc1[j] + bb[j], 0.f);
        }
    }

    // ---- P2: [128 x 128] @ [128 x 128], A redistributed per 32-col chunk ----
    float acc2_0[16], acc2_1[16];
    #pragma unroll
    for (int j = 0; j < 16; ++j) { acc2_0[j] = 0.f; acc2_1[j] = 0.f; }

    for (int c2 = 0; c2 < 4; ++c2) {
        const float* wsrc = P2wt + (size_t)c2 * 32 * D + tid * 8;
        float4 u0 = *(const float4*)wsrc;
        float4 u1 = *(const float4*)(wsrc + 4);
        __syncthreads();
        float* wp = s_w + (tid >> 4) * WS + (tid & 15) * 8;
        *(float4*)wp = u0; *((float4*)wp + 1) = u1;
        if ((w >> 1) == c2) {
            int kloc = (w & 1) * 16;
            float* d0 = s_a + a0base + kloc;
            float* d1 = s_a + a1base + kloc;
            #pragma unroll
            for (int j = 0; j < 16; ++j) { d0[j] = acc0[j]; d1[j] = acc1[j]; }
        }
        __syncthreads();
        #pragma unroll 8
        for (int kk = 0; kk < 32; ++kk) {
            float a0 = s_a[a0base + kk];
            float a1 = s_a[a1base + kk];
            const float4* wr = (const float4*)(s_w + kk * WS + c0);
            float4 w0 = wr[0], w1 = wr[1], w2 = wr[2], w3 = wr[3];
            FMA16(acc2_0, a0, w0, w1, w2, w3);
            FMA16(acc2_1, a1, w0, w1, w2, w3);
        }
    }

    // ---- P3: relu(acc2 + P2b) . P3w, partial per wave, reduce via LDS ----
    {
        float4 b0 = *(const float4*)(P2b + c0);
        float4 b1 = *(const float4*)(P2b + c0 + 4);
        float4 b2 = *(const float4*)(P2b + c0 + 8);
        float4 b3 = *(const float4*)(P2b + c0 + 12);
        float bb[16] = {b0.x, b0.y, b0.z, b0.w, b1.x, b1.y, b1.z, b1.w,
                        b2.x, b2.y, b2.z, b2.w, b3.x, b3.y, b3.z, b3.w};
        float4 p0v = *(const float4*)(P3w + c0);
        float4 p1v = *(const float4*)(P3w + c0 + 4);
        float4 p2v = *(const float4*)(P3w + c0 + 8);
        float4 p3v = *(const float4*)(P3w + c0 + 12);
        float pw[16] = {p0v.x, p0v.y, p0v.z, p0v.w, p1v.x, p1v.y, p1v.z, p1v.w,
                        p2v.x, p2v.y, p2v.z, p2v.w, p3v.x, p3v.y, p3v.z, p3v.w};
        float part0 = 0.f, part1 = 0.f;
        #pragma unroll
        for (int j = 0; j < 16; ++j) {
            part0 += fmaxf(acc2_0[j] + bb[j], 0.f) * pw[j];
            part1 += fmaxf(acc2_1[j] + bb[j], 0.f) * pw[j];
        }
        s_red[lane * 8 + w] = part0;
        s_red[(lane + 64) * 8 + w] = part1;
    }
    __syncthreads();
    if (tid < 128) {
        float s = 0.f;
        #pragma unroll
        for (int j = 0; j < 8; ++j) s += s_red[tid * 8 + j];
        int p = p0 + tid;
        if (p < twoEP) out[p] = s + P3b[0];
    }
}

static inline size_t align_up(size_t x, size_t a) { return (x + a - 1) & ~(a - 1); }

extern "C" void kernel_launch(void* const* d_in, const int* in_sizes, int n_in,
                              void* d_out, int out_size, void* d_ws, size_t ws_size,
                              hipStream_t stream) {
    const float* x        = (const float*)d_in[0];
    const int*   edge_src = (const int*)d_in[1];
    const int*   edge_dst = (const int*)d_in[2];
    const int*   pos_src  = (const int*)d_in[3];
    const int*   pos_dst  = (const int*)d_in[4];
    const int*   neg_src  = (const int*)d_in[5];
    const int*   neg_dst  = (const int*)d_in[6];
    const float* W1n = (const float*)d_in[7];
    const float* W1s = (const float*)d_in[8];
    const float* b1  = (const float*)d_in[9];
    const float* W2n = (const float*)d_in[10];
    const float* W2s = (const float*)d_in[11];
    const float* b2  = (const float*)d_in[12];
    const float* P1w = (const float*)d_in[13];
    const float* P1b = (const float*)d_in[14];
    const float* P2w = (const float*)d_in[15];
    const float* P2b = (const float*)d_in[16];
    const float* P3w = (const float*)d_in[17];
    const float* P3b = (const float*)d_in[18];
    float* out = (float*)d_out;

    const int N = in_sizes[0] / D;
    const int E = in_sizes[1];
    const int EP = in_sizes[3];

    char* ws = (char*)d_ws;
    size_t off = 0;
    int* row_off = (int*)(ws + off); off = align_up(off + (size_t)(N + 1) * 4, 256);
    int* cursor  = (int*)(ws + off); off = align_up(off + (size_t)N * 4, 256);
    int* bsums   = (int*)(ws + off); off = align_up(off + 4096, 256);
    int* csr     = (int*)(ws + off); off = align_up(off + (size_t)E * 4, 256);
    float* agg   = (float*)(ws + off); off = align_up(off + (size_t)N * D * 4, 256);
    float* h1    = (float*)(ws + off); off = align_up(off + (size_t)N * D * 4, 256);
    float* h2    = (float*)(ws + off); off = align_up(off + (size_t)N * D * 4, 256);
    float* Wt1   = (float*)(ws + off); off = align_up(off + (size_t)2 * D * D * 4, 256);
    float* Wt2   = (float*)(ws + off); off = align_up(off + (size_t)2 * D * D * 4, 256);
    float* P1wt  = (float*)(ws + off); off = align_up(off + (size_t)2 * D * D * 4, 256);
    float* P2wt  = (float*)(ws + off); off = align_up(off + (size_t)D * D * 4, 256);
    (void)ws_size;

    const int nb_scan = (N + SCAN_B - 1) / SCAN_B;

    // --- CSR build ---
    hipMemsetAsync(cursor, 0, (size_t)N * 4, stream);
    k_count_deg<<<(E + 255) / 256, 256, 0, stream>>>(edge_dst, cursor, E);
    k_scan_block<<<nb_scan, SCAN_B, 0, stream>>>(cursor, row_off, bsums, N);
    k_scan_sums<<<1, 64, 0, stream>>>(bsums, nb_scan);
    k_scan_add<<<nb_scan, SCAN_B, 0, stream>>>(row_off, bsums, N);
    hipMemsetAsync(cursor, 0, (size_t)N * 4, stream);
    k_scatter<<<(E + 255) / 256, 256, 0, stream>>>(edge_src, edge_dst, row_off, cursor, csr, E);

    // --- weight transposes (k-major) ---
    const int TB = (D * D + 255) / 256;
    k_transpose<<<TB, 256, 0, stream>>>(W1s, Wt1, D, D);
    k_transpose<<<TB, 256, 0, stream>>>(W1n, Wt1 + D * D, D, D);
    k_transpose<<<TB, 256, 0, stream>>>(W2s, Wt2, D, D);
    k_transpose<<<TB, 256, 0, stream>>>(W2n, Wt2 + D * D, D, D);
    k_transpose<<<2 * TB, 256, 0, stream>>>(P1w, P1wt, D, 2 * D);
    k_transpose<<<TB, 256, 0, stream>>>(P2w, P2wt, D, D);

    const int ngrid = (N + 127) / 128;
    const int pgrid = (2 * EP + 127) / 128;

    // --- layer 1 ---
    k_agg<<<(N + 7) / 8, 256, 0, stream>>>(x, row_off, csr, agg, N);
    k_transform<<<ngrid, 512, 0, stream>>>(x, agg, Wt1, b1, h1, N, 1);
    // --- layer 2 ---
    k_agg<<<(N + 7) / 8, 256, 0, stream>>>(h1, row_off, csr, agg, N);
    k_transform<<<ngrid, 512, 0, stream>>>(h1, agg, Wt2, b2, h2, N, 0);

    // --- fused predictor ---
    k_mlp<<<pgrid, 512, 0, stream>>>(h2, pos_src, pos_dst, neg_src, neg_dst,
                                     P1wt, P1b, P2wt, P2b, P3w, P3b, out, EP);
}

// Round 4
// 443.415 us; speedup vs baseline: 16.6331x; 2.0440x over previous
//
#include <hip/hip_runtime.h>
#include <hip/hip_bf16.h>
#include <hip/hip_fp16.h>

// GraphSAGE(2-layer, mean agg) + 3-layer MLP link predictor.
// N=100000, E=1.6M, E_PAIR=100000, D=128.
// Round 4: fp16 MFMA (16x16x32, fp32 accum) for all GEMMs; fp16 feature tables
// halve gather traffic. Weights consumed as-given [O][K] (B = W, no transpose).

#define D 128
#define SCAN_B 512
#define LDA 40       // f16 elems per staged-tile row (80B stride: 2-way banks = free)
#define LDH 136      // f16 elems per s_h row (272B stride: 2-way banks = free)

typedef _Float16 f16x8 __attribute__((ext_vector_type(8)));
typedef float f32x4 __attribute__((ext_vector_type(4)));

// ---------------- CSR build ----------------
__global__ void k_count_deg(const int* __restrict__ dst, int* __restrict__ cnt, int e) {
    int i = blockIdx.x * 256 + threadIdx.x;
    if (i < e) atomicAdd(&cnt[dst[i]], 1);
}

__global__ void k_scan_block(const int* __restrict__ deg, int* __restrict__ row_off,
                             int* __restrict__ bsums, int n) {
    __shared__ int s[SCAN_B];
    int i = blockIdx.x * SCAN_B + threadIdx.x;
    int v = (i < n) ? deg[i] : 0;
    s[threadIdx.x] = v;
    __syncthreads();
    for (int off = 1; off < SCAN_B; off <<= 1) {
        int add = (threadIdx.x >= off) ? s[threadIdx.x - off] : 0;
        __syncthreads();
        s[threadIdx.x] += add;
        __syncthreads();
    }
    if (i < n) row_off[i + 1] = s[threadIdx.x];
    if (threadIdx.x == SCAN_B - 1) bsums[blockIdx.x] = s[threadIdx.x];
}

__global__ void k_scan_sums(int* __restrict__ bsums, int nb) {
    if (blockIdx.x == 0 && threadIdx.x == 0) {
        int run = 0;
        for (int b = 0; b < nb; ++b) { int t = bsums[b]; bsums[b] = run; run += t; }
    }
}

__global__ void k_scan_add(int* __restrict__ row_off, const int* __restrict__ bsums, int n) {
    int i = blockIdx.x * SCAN_B + threadIdx.x;
    if (i < n) row_off[i + 1] += bsums[blockIdx.x];
    if (i == 0) row_off[0] = 0;
}

__global__ void k_scatter(const int* __restrict__ src, const int* __restrict__ dst,
                          const int* __restrict__ row_off, int* __restrict__ cursor,
                          int* __restrict__ csr, int e) {
    int i = blockIdx.x * 256 + threadIdx.x;
    if (i < e) {
        int d = dst[i];
        int p = atomicAdd(&cursor[d], 1);
        csr[row_off[d] + p] = src[i];
    }
}

// ---------------- f32 -> f16 convert (8 elems/thread) ----------------
__global__ void k_cvt_f16(const float* __restrict__ src, _Float16* __restrict__ dst, int n8) {
    int i = blockIdx.x * 256 + threadIdx.x;
    if (i >= n8) return;
    const float4* s4 = (const float4*)src;
    float4 a = s4[2 * i], b = s4[2 * i + 1];
    f16x8 h;
    h[0] = (_Float16)a.x; h[1] = (_Float16)a.y; h[2] = (_Float16)a.z; h[3] = (_Float16)a.w;
    h[4] = (_Float16)b.x; h[5] = (_Float16)b.y; h[6] = (_Float16)b.z; h[7] = (_Float16)b.w;
    *(f16x8*)(dst + 8 * i) = h;
}

// ---------------- mean aggregation: 16-lane group per node, f16 in/out ----------------
__global__ __launch_bounds__(256) void k_agg(
    const _Float16* __restrict__ Xf, const int* __restrict__ row_off,
    const int* __restrict__ csr, _Float16* __restrict__ Aggf, int n_nodes) {
    int g = blockIdx.x * 16 + (threadIdx.x >> 4);
    if (g >= n_nodes) return;
    int l = threadIdx.x & 15;
    int beg = row_off[g], end = row_off[g + 1];
    float a0[8] = {0.f, 0.f, 0.f, 0.f, 0.f, 0.f, 0.f, 0.f};
    float a1[8] = {0.f, 0.f, 0.f, 0.f, 0.f, 0.f, 0.f, 0.f};
    int i = beg;
    for (; i + 2 <= end; i += 2) {
        int s0 = csr[i], s1 = csr[i + 1];
        f16x8 v0 = *(const f16x8*)(Xf + (size_t)s0 * D + l * 8);
        f16x8 v1 = *(const f16x8*)(Xf + (size_t)s1 * D + l * 8);
        #pragma unroll
        for (int j = 0; j < 8; ++j) { a0[j] += (float)v0[j]; a1[j] += (float)v1[j]; }
    }
    if (i < end) {
        int s0 = csr[i];
        f16x8 v0 = *(const f16x8*)(Xf + (size_t)s0 * D + l * 8);
        #pragma unroll
        for (int j = 0; j < 8; ++j) a0[j] += (float)v0[j];
    }
    float inv = 1.0f / fmaxf((float)(end - beg), 1.0f);
    f16x8 o;
    #pragma unroll
    for (int j = 0; j < 8; ++j) o[j] = (_Float16)((a0[j] + a1[j]) * inv);
    *(f16x8*)(Aggf + (size_t)g * D + l * 8) = o;
}

// ---------------- layer transform (MFMA): out_f16 = relu?([X|Agg] @ [Ws;Wn]^T + b) ----------------
// 512 thr = 8 waves; block tile 128x128; wave (wr=w>>1, wc=w&1) owns rows [32wr,32wr+32), cols [64wc,64wc+64).
__global__ __launch_bounds__(512) void k_transform(
    const _Float16* __restrict__ Xf, const _Float16* __restrict__ Aggf,
    const _Float16* __restrict__ Wsf, const _Float16* __restrict__ Wnf,
    const float* __restrict__ bias, _Float16* __restrict__ outf,
    int n_rows, int do_relu) {
    __shared__ _Float16 s_a[128 * LDA];
    __shared__ _Float16 s_b[128 * LDA];
    int tid = threadIdx.x;
    int w = tid >> 6, l = tid & 63;
    int wr = w >> 1, wc = w & 1;
    int l15 = l & 15, lk = l >> 4;
    int n0 = blockIdx.x * 128;
    int r = tid >> 2, q = tid & 3;
    int rstage = n0 + r; if (rstage >= n_rows) rstage = n_rows - 1;

    f32x4 acc[2][4];
    #pragma unroll
    for (int i = 0; i < 2; ++i)
        #pragma unroll
        for (int j = 0; j < 4; ++j) acc[i][j] = (f32x4){0.f, 0.f, 0.f, 0.f};

    int a_off = (wr * 32 + l15) * LDA + lk * 8;
    int b_off = (wc * 64 + l15) * LDA + lk * 8;

    for (int c = 0; c < 8; ++c) {
        const _Float16* asrc = (c < 4) ? Xf : Aggf;
        const _Float16* wsrc = (c < 4) ? Wsf : Wnf;
        int kb = (c & 3) * 32;
        float4 av = *(const float4*)(asrc + (size_t)rstage * D + kb + q * 8);
        float4 wv = *(const float4*)(wsrc + (size_t)r * D + kb + q * 8);
        __syncthreads();
        *(float4*)(s_a + r * LDA + q * 8) = av;
        *(float4*)(s_b + r * LDA + q * 8) = wv;
        __syncthreads();
        f16x8 af[2], bf[4];
        af[0] = *(const f16x8*)(s_a + a_off);
        af[1] = *(const f16x8*)(s_a + a_off + 16 * LDA);
        #pragma unroll
        for (int j = 0; j < 4; ++j) bf[j] = *(const f16x8*)(s_b + b_off + j * 16 * LDA);
        #pragma unroll
        for (int i = 0; i < 2; ++i)
            #pragma unroll
            for (int j = 0; j < 4; ++j)
                acc[i][j] = __builtin_amdgcn_mfma_f32_16x16x32_f16(af[i], bf[j], acc[i][j], 0, 0, 0);
    }

    // epilogue: C layout col = l&15, row = (l>>4)*4 + v
    #pragma unroll
    for (int j = 0; j < 4; ++j) {
        int col = wc * 64 + j * 16 + l15;
        float bv = bias[col];
        #pragma unroll
        for (int i = 0; i < 2; ++i) {
            int rowb = n0 + wr * 32 + i * 16 + lk * 4;
            #pragma unroll
            for (int v = 0; v < 4; ++v) {
                int row = rowb + v;
                if (row < n_rows) {
                    float xv = acc[i][j][v] + bv;
                    if (do_relu) xv = fmaxf(xv, 0.f);
                    outf[(size_t)row * D + col] = (_Float16)xv;
                }
            }
        }
    }
}

// ---------------- fused predictor (MFMA): gather-cat -> P1 -> relu -> P2 -> relu -> P3 ----------------
__global__ __launch_bounds__(512) void k_mlp(
    const _Float16* __restrict__ Hf,
    const int* __restrict__ pos_src, const int* __restrict__ pos_dst,
    const int* __restrict__ neg_src, const int* __restrict__ neg_dst,
    const _Float16* __restrict__ P1wf, const float* __restrict__ P1b,
    const _Float16* __restrict__ P2wf, const float* __restrict__ P2b,
    const float* __restrict__ P3w, const float* __restrict__ P3b,
    float* __restrict__ out, int EP) {
    __shared__ _Float16 s_a[128 * LDA];
    __shared__ _Float16 s_b[128 * LDA];
    __shared__ _Float16 s_h[128 * LDH];
    __shared__ float s_red[128 * 2];
    __shared__ int s_src[128], s_dst[128];
    int tid = threadIdx.x;
    int w = tid >> 6, l = tid & 63;
    int wr = w >> 1, wc = w & 1;
    int l15 = l & 15, lk = l >> 4;
    int p0 = blockIdx.x * 128;
    int twoEP = 2 * EP;
    int r = tid >> 2, q = tid & 3;

    if (tid < 128) {
        int p = p0 + tid;
        if (p >= twoEP) p = twoEP - 1;
        int s, d;
        if (p < EP) { s = pos_src[p]; d = pos_dst[p]; }
        else { s = neg_src[p - EP]; d = neg_dst[p - EP]; }
        s_src[tid] = s; s_dst[tid] = d;
    }
    __syncthreads();

    int a_off = (wr * 32 + l15) * LDA + lk * 8;
    int b_off = (wc * 64 + l15) * LDA + lk * 8;

    f32x4 acc[2][4];
    #pragma unroll
    for (int i = 0; i < 2; ++i)
        #pragma unroll
        for (int j = 0; j < 4; ++j) acc[i][j] = (f32x4){0.f, 0.f, 0.f, 0.f};

    // ---- P1: [128 x 256] @ W1^T, cat = [h_src | h_dst] ----
    for (int c = 0; c < 8; ++c) {
        int node = (c < 4) ? s_src[r] : s_dst[r];
        int kb = (c & 3) * 32;
        float4 av = *(const float4*)(Hf + (size_t)node * D + kb + q * 8);
        float4 wv = *(const float4*)(P1wf + (size_t)r * 256 + c * 32 + q * 8);
        __syncthreads();
        *(float4*)(s_a + r * LDA + q * 8) = av;
        *(float4*)(s_b + r * LDA + q * 8) = wv;
        __syncthreads();
        f16x8 af[2], bf[4];
        af[0] = *(const f16x8*)(s_a + a_off);
        af[1] = *(const f16x8*)(s_a + a_off + 16 * LDA);
        #pragma unroll
        for (int j = 0; j < 4; ++j) bf[j] = *(const f16x8*)(s_b + b_off + j * 16 * LDA);
        #pragma unroll
        for (int i = 0; i < 2; ++i)
            #pragma unroll
            for (int j = 0; j < 4; ++j)
                acc[i][j] = __builtin_amdgcn_mfma_f32_16x16x32_f16(af[i], bf[j], acc[i][j], 0, 0, 0);
    }

    // h1 = relu(acc + P1b) -> s_h[row][col] (f16)
    #pragma unroll
    for (int j = 0; j < 4; ++j) {
        int col = wc * 64 + j * 16 + l15;
        float bv = P1b[col];
        #pragma unroll
        for (int i = 0; i < 2; ++i) {
            int rowb = wr * 32 + i * 16 + lk * 4;
            #pragma unroll
            for (int v = 0; v < 4; ++v)
                s_h[(rowb + v) * LDH + col] = (_Float16)fmaxf(acc[i][j][v] + bv, 0.f);
        }
    }

    // ---- P2: [128 x 128] @ W2^T, A from s_h ----
    f32x4 acc2[2][4];
    #pragma unroll
    for (int i = 0; i < 2; ++i)
        #pragma unroll
        for (int j = 0; j < 4; ++j) acc2[i][j] = (f32x4){0.f, 0.f, 0.f, 0.f};

    for (int c2 = 0; c2 < 4; ++c2) {
        float4 wv = *(const float4*)(P2wf + (size_t)r * D + c2 * 32 + q * 8);
        __syncthreads();   // covers s_h writes (c2==0) and prior s_b reads
        *(float4*)(s_b + r * LDA + q * 8) = wv;
        __syncthreads();
        f16x8 af[2], bf[4];
        af[0] = *(const f16x8*)(s_h + (wr * 32 + l15) * LDH + c2 * 32 + lk * 8);
        af[1] = *(const f16x8*)(s_h + (wr * 32 + 16 + l15) * LDH + c2 * 32 + lk * 8);
        #pragma unroll
        for (int j = 0; j < 4; ++j) bf[j] = *(const f16x8*)(s_b + b_off + j * 16 * LDA);
        #pragma unroll
        for (int i = 0; i < 2; ++i)
            #pragma unroll
            for (int j = 0; j < 4; ++j)
                acc2[i][j] = __builtin_amdgcn_mfma_f32_16x16x32_f16(af[i], bf[j], acc2[i][j], 0, 0, 0);
    }

    // ---- P3: relu(acc2 + P2b) . P3w ----
    float b2v[4], pw[4];
    #pragma unroll
    for (int j = 0; j < 4; ++j) {
        int col = wc * 64 + j * 16 + l15;
        b2v[j] = P2b[col];
        pw[j] = P3w[col];
    }
    #pragma unroll
    for (int i = 0; i < 2; ++i) {
        #pragma unroll
        for (int v = 0; v < 4; ++v) {
            float s = 0.f;
            #pragma unroll
            for (int j = 0; j < 4; ++j)
                s += fmaxf(acc2[i][j][v] + b2v[j], 0.f) * pw[j];
            s += __shfl_xor(s, 1);
            s += __shfl_xor(s, 2);
            s += __shfl_xor(s, 4);
            s += __shfl_xor(s, 8);
            if (l15 == 0)
                s_red[(wr * 32 + i * 16 + lk * 4 + v) * 2 + wc] = s;
        }
    }
    __syncthreads();
    if (tid < 128) {
        int p = p0 + tid;
        if (p < twoEP) out[p] = s_red[tid * 2] + s_red[tid * 2 + 1] + P3b[0];
    }
}

static inline size_t align_up(size_t x, size_t a) { return (x + a - 1) & ~(a - 1); }

extern "C" void kernel_launch(void* const* d_in, const int* in_sizes, int n_in,
                              void* d_out, int out_size, void* d_ws, size_t ws_size,
                              hipStream_t stream) {
    const float* x        = (const float*)d_in[0];
    const int*   edge_src = (const int*)d_in[1];
    const int*   edge_dst = (const int*)d_in[2];
    const int*   pos_src  = (const int*)d_in[3];
    const int*   pos_dst  = (const int*)d_in[4];
    const int*   neg_src  = (const int*)d_in[5];
    const int*   neg_dst  = (const int*)d_in[6];
    const float* W1n = (const float*)d_in[7];
    const float* W1s = (const float*)d_in[8];
    const float* b1  = (const float*)d_in[9];
    const float* W2n = (const float*)d_in[10];
    const float* W2s = (const float*)d_in[11];
    const float* b2  = (const float*)d_in[12];
    const float* P1w = (const float*)d_in[13];
    const float* P1b = (const float*)d_in[14];
    const float* P2w = (const float*)d_in[15];
    const float* P2b = (const float*)d_in[16];
    const float* P3w = (const float*)d_in[17];
    const float* P3b = (const float*)d_in[18];
    float* out = (float*)d_out;

    const int N = in_sizes[0] / D;
    const int E = in_sizes[1];
    const int EP = in_sizes[3];

    char* ws = (char*)d_ws;
    size_t off = 0;
    int* row_off = (int*)(ws + off); off = align_up(off + (size_t)(N + 1) * 4, 256);
    int* cursor  = (int*)(ws + off); off = align_up(off + (size_t)N * 4, 256);
    int* bsums   = (int*)(ws + off); off = align_up(off + 4096, 256);
    int* csr     = (int*)(ws + off); off = align_up(off + (size_t)E * 4, 256);
    _Float16* xf   = (_Float16*)(ws + off); off = align_up(off + (size_t)N * D * 2, 256);
    _Float16* aggf = (_Float16*)(ws + off); off = align_up(off + (size_t)N * D * 2, 256);
    _Float16* h1f  = (_Float16*)(ws + off); off = align_up(off + (size_t)N * D * 2, 256);
    _Float16* h2f  = (_Float16*)(ws + off); off = align_up(off + (size_t)N * D * 2, 256);
    _Float16* Ws1f = (_Float16*)(ws + off); off = align_up(off + (size_t)D * D * 2, 256);
    _Float16* Wn1f = (_Float16*)(ws + off); off = align_up(off + (size_t)D * D * 2, 256);
    _Float16* Ws2f = (_Float16*)(ws + off); off = align_up(off + (size_t)D * D * 2, 256);
    _Float16* Wn2f = (_Float16*)(ws + off); off = align_up(off + (size_t)D * D * 2, 256);
    _Float16* P1wf = (_Float16*)(ws + off); off = align_up(off + (size_t)2 * D * D * 2, 256);
    _Float16* P2wf = (_Float16*)(ws + off); off = align_up(off + (size_t)D * D * 2, 256);
    (void)ws_size;

    const int nb_scan = (N + SCAN_B - 1) / SCAN_B;

    // --- CSR build ---
    hipMemsetAsync(cursor, 0, (size_t)N * 4, stream);
    k_count_deg<<<(E + 255) / 256, 256, 0, stream>>>(edge_dst, cursor, E);
    k_scan_block<<<nb_scan, SCAN_B, 0, stream>>>(cursor, row_off, bsums, N);
    k_scan_sums<<<1, 64, 0, stream>>>(bsums, nb_scan);
    k_scan_add<<<nb_scan, SCAN_B, 0, stream>>>(row_off, bsums, N);
    hipMemsetAsync(cursor, 0, (size_t)N * 4, stream);
    k_scatter<<<(E + 255) / 256, 256, 0, stream>>>(edge_src, edge_dst, row_off, cursor, csr, E);

    // --- f16 conversions ---
    k_cvt_f16<<<(N * D / 8 + 255) / 256, 256, 0, stream>>>(x, xf, N * D / 8);
    k_cvt_f16<<<(D * D / 8 + 255) / 256, 256, 0, stream>>>(W1s, Ws1f, D * D / 8);
    k_cvt_f16<<<(D * D / 8 + 255) / 256, 256, 0, stream>>>(W1n, Wn1f, D * D / 8);
    k_cvt_f16<<<(D * D / 8 + 255) / 256, 256, 0, stream>>>(W2s, Ws2f, D * D / 8);
    k_cvt_f16<<<(D * D / 8 + 255) / 256, 256, 0, stream>>>(W2n, Wn2f, D * D / 8);
    k_cvt_f16<<<(2 * D * D / 8 + 255) / 256, 256, 0, stream>>>(P1w, P1wf, 2 * D * D / 8);
    k_cvt_f16<<<(D * D / 8 + 255) / 256, 256, 0, stream>>>(P2w, P2wf, D * D / 8);

    const int ngrid = (N + 127) / 128;
    const int pgrid = (2 * EP + 127) / 128;

    // --- layer 1 ---
    k_agg<<<(N + 15) / 16, 256, 0, stream>>>(xf, row_off, csr, aggf, N);
    k_transform<<<ngrid, 512, 0, stream>>>(xf, aggf, Ws1f, Wn1f, b1, h1f, N, 1);
    // --- layer 2 ---
    k_agg<<<(N + 15) / 16, 256, 0, stream>>>(h1f, row_off, csr, aggf, N);
    k_transform<<<ngrid, 512, 0, stream>>>(h1f, aggf, Ws2f, Wn2f, b2, h2f, N, 0);

    // --- fused predictor ---
    k_mlp<<<pgrid, 512, 0, stream>>>(h2f, pos_src, pos_dst, neg_src, neg_dst,
                                     P1wf, P1b, P2wf, P2b, P3w, P3b, out, EP);
}